// Round 1
// baseline (478.709 us; speedup 1.0000x reference)
//
#include <hip/hip_runtime.h>
#include <hip/hip_bf16.h>

#define HW_W 640
#define HW_H 480

// One thread per event. events laid out row-major [N,4]: (x, y, t, p).
// Binarized output => racy plain stores of 1.0f are correct (idempotent),
// no atomics required. t is unused by the reference output.
__global__ void __launch_bounds__(256)
event_scatter_kernel(const float4* __restrict__ events,
                     float* __restrict__ out, int n) {
    int i = blockIdx.x * blockDim.x + threadIdx.x;
    if (i < n) {
        float4 e = events[i];                      // coalesced 16 B/lane
        // idx = x + W*y + W*H*((p+1)/2); exact in fp32 (all values < 2^24)
        float p01 = (e.w + 1.0f) * 0.5f;           // {-1,1} -> {0,1}
        int idx = (int)(e.x + (float)HW_W * e.y + (float)(HW_W * HW_H) * p01);
        out[idx] = 1.0f;
    }
}

extern "C" void kernel_launch(void* const* d_in, const int* in_sizes, int n_in,
                              void* d_out, int out_size, void* d_ws, size_t ws_size,
                              hipStream_t stream) {
    const float4* events = (const float4*)d_in[0];
    float* out = (float*)d_out;
    int n = in_sizes[0] / 4;                       // in_sizes[0] = N*4 flat elems

    // d_out is re-poisoned to 0xAA before every timed call — zero it first.
    hipMemsetAsync(d_out, 0, (size_t)out_size * sizeof(float), stream);

    int block = 256;
    int grid = (n + block - 1) / block;
    event_scatter_kernel<<<grid, block, 0, stream>>>(events, out, n);
}

// Round 2
// 433.890 us; speedup vs baseline: 1.1033x; 1.1033x over previous
//
#include <hip/hip_runtime.h>
#include <hip/hip_bf16.h>

#define HW_W 640
#define HW_H 480

typedef float vf4 __attribute__((ext_vector_type(4)));

// One thread per event. events laid out row-major [N,4]: (x, y, t, p).
// Binarized output => racy plain stores of 1.0f are correct (idempotent).
//
// R1 lesson: the 268 MB event stream thrashes L2 and evicts the dirty 2.4 MB
// scatter region, turning each 4 B store into a ~64 B partial-line writeback
// (WRITE_SIZE was 630 MB). Non-temporal event loads keep the stream from
// allocating in L2, so scatter lines stay resident and write back ~once.
__global__ void __launch_bounds__(256)
event_scatter_kernel(const vf4* __restrict__ events,
                     float* __restrict__ out, int n) {
    int i = blockIdx.x * blockDim.x + threadIdx.x;
    if (i < n) {
        vf4 e = __builtin_nontemporal_load(events + i);   // 16 B/lane, nt
        // idx = x + W*y + W*H*((p+1)/2); exact in fp32 (all values < 2^24)
        float p01 = (e.w + 1.0f) * 0.5f;                  // {-1,1} -> {0,1}
        int idx = (int)(e.x + (float)HW_W * e.y + (float)(HW_W * HW_H) * p01);
        out[idx] = 1.0f;                                   // cached store
    }
}

extern "C" void kernel_launch(void* const* d_in, const int* in_sizes, int n_in,
                              void* d_out, int out_size, void* d_ws, size_t ws_size,
                              hipStream_t stream) {
    const vf4* events = (const vf4*)d_in[0];
    float* out = (float*)d_out;
    int n = in_sizes[0] / 4;                       // in_sizes[0] = N*4 flat elems

    // d_out is re-poisoned to 0xAA before every timed call — zero it first.
    hipMemsetAsync(d_out, 0, (size_t)out_size * sizeof(float), stream);

    int block = 256;
    int grid = (n + block - 1) / block;
    event_scatter_kernel<<<grid, block, 0, stream>>>(events, out, n);
}

// Round 3
// 372.449 us; speedup vs baseline: 1.2853x; 1.1650x over previous
//
#include <hip/hip_runtime.h>
#include <hip/hip_bf16.h>

#define EW 640
#define EH 480
#define NVOX (2 * EH * EW)     // 614400 voxels
#define NWORDS (NVOX / 32)     // 19200 uint32 words = 76800 B bitmap
#define BLK 512

typedef float vf4 __attribute__((ext_vector_type(4)));

__device__ __forceinline__ int ev_idx(vf4 e) {
    // idx = x + W*y + W*H*((p+1)/2); exact in fp32 (all values < 2^24)
    float p01 = (e.w + 1.0f) * 0.5f;   // {-1,1} -> {0,1}
    return (int)(e.x + (float)EW * e.y + (float)(EW * EH) * p01);
}

// Full-voxel-space bitmap in LDS (76.8 KB; 2 blocks/CU on gfx950's 160 KB).
// Events stream through with 4 independent float4 loads in flight per thread;
// bits accumulate via LDS atomicOr (random banks ~2-way aliasing: free).
// At the end each block ORs its non-zero words into the global bitmap.
__global__ void __launch_bounds__(BLK, 4)   // 4 waves/EU -> 2 blocks/CU
event_bitmap_kernel(const vf4* __restrict__ events,
                    unsigned int* __restrict__ gbm, int n) {
    __shared__ unsigned int bm[NWORDS];
    for (int w = threadIdx.x; w < NWORDS; w += BLK) bm[w] = 0u;
    __syncthreads();

    const int nth = gridDim.x * BLK;
    int i = blockIdx.x * BLK + threadIdx.x;
    for (; i + 3 * nth < n; i += 4 * nth) {
        vf4 e0 = events[i];
        vf4 e1 = events[i + nth];
        vf4 e2 = events[i + 2 * nth];
        vf4 e3 = events[i + 3 * nth];
        int x0 = ev_idx(e0), x1 = ev_idx(e1), x2 = ev_idx(e2), x3 = ev_idx(e3);
        atomicOr(&bm[x0 >> 5], 1u << (x0 & 31));
        atomicOr(&bm[x1 >> 5], 1u << (x1 & 31));
        atomicOr(&bm[x2 >> 5], 1u << (x2 & 31));
        atomicOr(&bm[x3 >> 5], 1u << (x3 & 31));
    }
    for (; i < n; i += nth) {
        vf4 e = events[i];
        int x = ev_idx(e);
        atomicOr(&bm[x >> 5], 1u << (x & 31));
    }
    __syncthreads();

    for (int w = threadIdx.x; w < NWORDS; w += BLK) {
        unsigned int v = bm[w];
        if (v) atomicOr(&gbm[w], v);   // device-scope, L2-resident 76.8 KB
    }
}

// Bitmap -> float output. Writes every element, so no d_out memset needed.
__global__ void __launch_bounds__(256)
expand_kernel(const unsigned int* __restrict__ gbm, float* __restrict__ out) {
    int i = blockIdx.x * 256 + threadIdx.x;
    if (i < NVOX) {
        unsigned int wv = gbm[i >> 5];
        out[i] = ((wv >> (i & 31)) & 1u) ? 1.0f : 0.0f;
    }
}

extern "C" void kernel_launch(void* const* d_in, const int* in_sizes, int n_in,
                              void* d_out, int out_size, void* d_ws, size_t ws_size,
                              hipStream_t stream) {
    const vf4* events = (const vf4*)d_in[0];
    unsigned int* gbm = (unsigned int*)d_ws;   // 76.8 KB global bitmap scratch
    float* out = (float*)d_out;
    int n = in_sizes[0] / 4;                   // in_sizes[0] = N*4 flat elems

    // d_ws is re-poisoned to 0xAA before every timed call — zero the bitmap.
    hipMemsetAsync(gbm, 0, NWORDS * sizeof(unsigned int), stream);

    event_bitmap_kernel<<<512, BLK, 0, stream>>>(events, gbm, n);
    expand_kernel<<<(NVOX + 255) / 256, 256, 0, stream>>>(gbm, out);
}

// Round 4
// 369.327 us; speedup vs baseline: 1.2962x; 1.0085x over previous
//
#include <hip/hip_runtime.h>
#include <hip/hip_bf16.h>

#define EW 640
#define EH 480
#define NVOX (2 * EH * EW)     // 614400 voxels
#define NWORDS (NVOX / 32)     // 19200 uint32 words = 76800 B bitmap
#define BLK 512
#define NBLOCKS 512            // stage-1 grid (= 2 blocks/CU resident)
#define NCHUNK 8               // stage-2 partial count (64 bitmaps each)

typedef float vf4 __attribute__((ext_vector_type(4)));

__device__ __forceinline__ int ev_idx(vf4 e) {
    // idx = x + W*y + W*H*((p+1)/2); exact in fp32 (all values < 2^24)
    float p01 = (e.w + 1.0f) * 0.5f;   // {-1,1} -> {0,1}
    return (int)(e.x + (float)EW * e.y + (float)(EW * EH) * p01);
}

// Stage 1: per-block full-voxel-space bitmap in LDS (76.8 KB; 2 blocks/CU),
// then write the WHOLE bitmap to a private d_ws slice with plain coalesced
// stores. No global atomics (R3 lesson: 8M contended atomicOr ≈ 80 µs).
__global__ void __launch_bounds__(BLK, 4)
event_bitmap_kernel(const vf4* __restrict__ events,
                    unsigned int* __restrict__ bms, int n) {
    __shared__ unsigned int bm[NWORDS];
    for (int w = threadIdx.x; w < NWORDS; w += BLK) bm[w] = 0u;
    __syncthreads();

    const int nth = gridDim.x * BLK;
    int i = blockIdx.x * BLK + threadIdx.x;
    for (; i + 3 * nth < n; i += 4 * nth) {
        vf4 e0 = events[i];
        vf4 e1 = events[i + nth];
        vf4 e2 = events[i + 2 * nth];
        vf4 e3 = events[i + 3 * nth];
        int x0 = ev_idx(e0), x1 = ev_idx(e1), x2 = ev_idx(e2), x3 = ev_idx(e3);
        atomicOr(&bm[x0 >> 5], 1u << (x0 & 31));
        atomicOr(&bm[x1 >> 5], 1u << (x1 & 31));
        atomicOr(&bm[x2 >> 5], 1u << (x2 & 31));
        atomicOr(&bm[x3 >> 5], 1u << (x3 & 31));
    }
    for (; i < n; i += nth) {
        vf4 e = events[i];
        int x = ev_idx(e);
        atomicOr(&bm[x >> 5], 1u << (x & 31));
    }
    __syncthreads();

    // Full writeout (also overwrites the 0xAA ws poison). uint4-vectorized.
    uint4* dst = (uint4*)(bms + (size_t)blockIdx.x * NWORDS);
    const uint4* src = (const uint4*)bm;
    for (int w = threadIdx.x; w < NWORDS / 4; w += BLK) dst[w] = src[w];
}

// Stage 2: OR-reduce 512 bitmaps into NCHUNK partials. Coalesced, atomic-free.
// grid = (NWORDS/256, NCHUNK), block = 256.
__global__ void __launch_bounds__(256)
reduce_kernel(const unsigned int* __restrict__ bms,
              unsigned int* __restrict__ partial) {
    int w = blockIdx.x * 256 + threadIdx.x;
    int b0 = blockIdx.y * (NBLOCKS / NCHUNK);
    unsigned int acc = 0u;
    #pragma unroll 8
    for (int b = 0; b < NBLOCKS / NCHUNK; ++b)
        acc |= bms[(size_t)(b0 + b) * NWORDS + w];
    partial[(size_t)blockIdx.y * NWORDS + w] = acc;
}

// Stage 3: OR the partials, expand each word to 32 floats (8 float4 stores).
// Writes every output element, so no d_out memset needed.
__global__ void __launch_bounds__(256)
expand_kernel(const unsigned int* __restrict__ partial,
              float* __restrict__ out) {
    int w = blockIdx.x * 256 + threadIdx.x;   // word index [0, NWORDS)
    unsigned int acc = 0u;
    #pragma unroll
    for (int c = 0; c < NCHUNK; ++c)
        acc |= partial[(size_t)c * NWORDS + w];
    vf4* dst = (vf4*)(out + (size_t)w * 32);
    #pragma unroll
    for (int q = 0; q < 8; ++q) {
        vf4 v;
        v.x = (acc >> (q * 4 + 0)) & 1u ? 1.0f : 0.0f;
        v.y = (acc >> (q * 4 + 1)) & 1u ? 1.0f : 0.0f;
        v.z = (acc >> (q * 4 + 2)) & 1u ? 1.0f : 0.0f;
        v.w = (acc >> (q * 4 + 3)) & 1u ? 1.0f : 0.0f;
        dst[q] = v;
    }
}

extern "C" void kernel_launch(void* const* d_in, const int* in_sizes, int n_in,
                              void* d_out, int out_size, void* d_ws, size_t ws_size,
                              hipStream_t stream) {
    const vf4* events = (const vf4*)d_in[0];
    float* out = (float*)d_out;
    int n = in_sizes[0] / 4;                   // in_sizes[0] = N*4 flat elems

    unsigned int* bms = (unsigned int*)d_ws;                     // 512 bitmaps, 39.3 MB
    unsigned int* partial = bms + (size_t)NBLOCKS * NWORDS;      // 8 partials, 614 KB

    event_bitmap_kernel<<<NBLOCKS, BLK, 0, stream>>>(events, bms, n);
    reduce_kernel<<<dim3(NWORDS / 256, NCHUNK), 256, 0, stream>>>(bms, partial);
    expand_kernel<<<NWORDS / 256, 256, 0, stream>>>(partial, out);
}

// Round 5
// 364.280 us; speedup vs baseline: 1.3141x; 1.0139x over previous
//
#include <hip/hip_runtime.h>
#include <hip/hip_bf16.h>

#define EW 640
#define EH 480
#define NVOX (2 * EH * EW)     // 614400 voxels
#define NWORDS (NVOX / 32)     // 19200 uint32 words = 76800 B bitmap
#define BLKA 1024              // stage-1 block (16 waves)
#define NBLK_A 256             // stage-1 grid (1 block/CU) -> 256 bitmaps, 19.6 MB
#define NCHUNK 16              // stage-2 partials (16 bitmaps each)

typedef float vf4 __attribute__((ext_vector_type(4)));

__device__ __forceinline__ int ev_idx(vf4 e) {
    // idx = x + W*y + W*H*((p+1)/2); exact in fp32 (all values < 2^24)
    float p01 = (e.w + 1.0f) * 0.5f;   // {-1,1} -> {0,1}
    return (int)(e.x + (float)EW * e.y + (float)(EW * EH) * p01);
}

// Stage 1: per-block full-voxel-space bitmap in LDS (76.8 KB), 8 independent
// float4 loads in flight per thread (R4 lesson: 4-deep left the event loop at
// ~2.4 TB/s while HBM also drains the harness's dirty-fill backlog).
__global__ void __launch_bounds__(BLKA, 4)
event_bitmap_kernel(const vf4* __restrict__ events,
                    unsigned int* __restrict__ bms, int n) {
    __shared__ unsigned int bm[NWORDS];
    for (int w = threadIdx.x; w < NWORDS; w += BLKA) bm[w] = 0u;
    __syncthreads();

    const int nth = gridDim.x * BLKA;   // 262144
    int i = blockIdx.x * BLKA + threadIdx.x;
    for (; i + 7 * nth < n; i += 8 * nth) {
        vf4 e0 = events[i];
        vf4 e1 = events[i + nth];
        vf4 e2 = events[i + 2 * nth];
        vf4 e3 = events[i + 3 * nth];
        vf4 e4 = events[i + 4 * nth];
        vf4 e5 = events[i + 5 * nth];
        vf4 e6 = events[i + 6 * nth];
        vf4 e7 = events[i + 7 * nth];
        int x0 = ev_idx(e0), x1 = ev_idx(e1), x2 = ev_idx(e2), x3 = ev_idx(e3);
        int x4 = ev_idx(e4), x5 = ev_idx(e5), x6 = ev_idx(e6), x7 = ev_idx(e7);
        atomicOr(&bm[x0 >> 5], 1u << (x0 & 31));
        atomicOr(&bm[x1 >> 5], 1u << (x1 & 31));
        atomicOr(&bm[x2 >> 5], 1u << (x2 & 31));
        atomicOr(&bm[x3 >> 5], 1u << (x3 & 31));
        atomicOr(&bm[x4 >> 5], 1u << (x4 & 31));
        atomicOr(&bm[x5 >> 5], 1u << (x5 & 31));
        atomicOr(&bm[x6 >> 5], 1u << (x6 & 31));
        atomicOr(&bm[x7 >> 5], 1u << (x7 & 31));
    }
    for (; i < n; i += nth) {
        vf4 e = events[i];
        int x = ev_idx(e);
        atomicOr(&bm[x >> 5], 1u << (x & 31));
    }
    __syncthreads();

    // Full coalesced writeout of this block's bitmap (overwrites ws poison).
    uint4* dst = (uint4*)(bms + (size_t)blockIdx.x * NWORDS);
    const uint4* src = (const uint4*)bm;
    for (int w = threadIdx.x; w < NWORDS / 4; w += BLKA) dst[w] = src[w];
}

// Stage 2: OR-reduce 256 bitmaps -> 16 partials. grid (NWORDS/256, NCHUNK).
__global__ void __launch_bounds__(256)
reduce_kernel(const unsigned int* __restrict__ bms,
              unsigned int* __restrict__ partial) {
    int w = blockIdx.x * 256 + threadIdx.x;
    int b0 = blockIdx.y * (NBLK_A / NCHUNK);
    unsigned int acc = 0u;
    #pragma unroll
    for (int b = 0; b < NBLK_A / NCHUNK; ++b)
        acc |= bms[(size_t)(b0 + b) * NWORDS + w];
    partial[(size_t)blockIdx.y * NWORDS + w] = acc;
}

// Stage 3: OR the 16 partials, expand words -> floats via LDS staging so all
// float4 stores are fully coalesced. Block covers 256 words = 8192 floats.
__global__ void __launch_bounds__(256)
expand_kernel(const unsigned int* __restrict__ partial,
              float* __restrict__ out) {
    __shared__ unsigned int sbm[256];
    int w = blockIdx.x * 256 + threadIdx.x;
    unsigned int acc = 0u;
    #pragma unroll
    for (int c = 0; c < NCHUNK; ++c)
        acc |= partial[(size_t)c * NWORDS + w];
    sbm[threadIdx.x] = acc;
    __syncthreads();

    vf4* out4 = (vf4*)out + (size_t)blockIdx.x * 2048;   // 2048 float4 / block
    #pragma unroll
    for (int q = 0; q < 8; ++q) {
        int f = q * 256 + threadIdx.x;        // local float4 index [0,2048)
        unsigned int wv = sbm[f >> 3];        // 8 lanes share a word: broadcast
        int sh = (f & 7) * 4;
        vf4 v;
        v.x = (wv >> (sh + 0)) & 1u ? 1.0f : 0.0f;
        v.y = (wv >> (sh + 1)) & 1u ? 1.0f : 0.0f;
        v.z = (wv >> (sh + 2)) & 1u ? 1.0f : 0.0f;
        v.w = (wv >> (sh + 3)) & 1u ? 1.0f : 0.0f;
        out4[f] = v;
    }
}

extern "C" void kernel_launch(void* const* d_in, const int* in_sizes, int n_in,
                              void* d_out, int out_size, void* d_ws, size_t ws_size,
                              hipStream_t stream) {
    const vf4* events = (const vf4*)d_in[0];
    float* out = (float*)d_out;
    int n = in_sizes[0] / 4;                   // in_sizes[0] = N*4 flat elems

    unsigned int* bms = (unsigned int*)d_ws;                 // 256 bitmaps, 19.6 MB
    unsigned int* partial = bms + (size_t)NBLK_A * NWORDS;   // 16 partials, 1.2 MB

    // Every ws/out byte we rely on is fully written by the kernels: no memsets.
    event_bitmap_kernel<<<NBLK_A, BLKA, 0, stream>>>(events, bms, n);
    reduce_kernel<<<dim3(NWORDS / 256, NCHUNK), 256, 0, stream>>>(bms, partial);
    expand_kernel<<<NWORDS / 256, 256, 0, stream>>>(partial, out);
}